// Round 12
// baseline (116.590 us; speedup 1.0000x reference)
//
#include <hip/hip_runtime.h>

#define IN_F 1024
#define OUT_F 1024
#define NTOK 32768
#define BM 256
#define BN 256
#define BK 64
#define KT (IN_F / BK)  // 16 K-tiles

typedef __bf16 bf16;
typedef __bf16 bf16x4 __attribute__((ext_vector_type(4)));
typedef __bf16 bf16x8 __attribute__((ext_vector_type(8)));
typedef float f32x4 __attribute__((ext_vector_type(4)));

// ---------------------------------------------------------------------------
// Kernel 1: build patched bf16 weight W' (validated rounds 1-9).
// ---------------------------------------------------------------------------
__global__ void build_wp(const float* __restrict__ W,
                         const int* __restrict__ rows,
                         const int* __restrict__ srcs,
                         const int* __restrict__ clones,
                         bf16* __restrict__ Wp) {
  const int r = blockIdx.x;
  const int row = rows[r];
  const int s = srcs[r];
  const int c0 = clones[3 * r + 0];
  const int c1 = clones[3 * r + 1];
  const int c2 = clones[3 * r + 2];
  const float* wr = W + (size_t)row * IN_F;
  const float fixv = 0.25f * (wr[s] + wr[c0] + wr[c1] + wr[c2]);

  const int col = threadIdx.x * 4;
  f32x4 v = *reinterpret_cast<const f32x4*>(wr + col);
  bf16x4 o;
#pragma unroll
  for (int j = 0; j < 4; ++j) {
    const int c = col + j;
    float f = v[j];
    if (c == c0 || c == c1 || c == c2) f = 0.0f;
    if (c == s) f = fixv;
    o[j] = (bf16)f;
  }
  *reinterpret_cast<bf16x4*>(Wp + (size_t)row * IN_F + col) = o;
}

// ---------------------------------------------------------------------------
// Kernel 1b: pre-pass — X (fp32) -> Xb (bf16), tile-linearized, swizzle baked.
// Xb image for (bm,t): row r at byte r*128, phys 16B-slot p holds logical
// k-chunk s = p ^ (r&7) (k-cols t*64 + s*8 .. +8).
// ---------------------------------------------------------------------------
__global__ void prep_xb(const float* __restrict__ X, bf16* __restrict__ Xb) {
  const int c = blockIdx.x * 256 + threadIdx.x;  // 0 .. 4194303
  const int q = c & 2047;                        // 16B chunk within tile image
  const int bmt = c >> 11;                       // bm*16 + t
  const int bm = bmt >> 4;
  const int t = bmt & 15;
  const int row = q >> 3;
  const int p = q & 7;
  const int s = p ^ (row & 7);
  const float* src = X + ((size_t)bm * BM + row) * IN_F + t * BK + s * 8;
  const f32x4 a = *reinterpret_cast<const f32x4*>(src);
  const f32x4 b = *reinterpret_cast<const f32x4*>(src + 4);
  bf16x8 o;
#pragma unroll
  for (int j = 0; j < 4; ++j) {
    o[j] = (bf16)a[j];
    o[4 + j] = (bf16)b[j];
  }
  *reinterpret_cast<bf16x8*>(Xb + (size_t)c * 8) = o;
}

// ---------------------------------------------------------------------------
// Kernel 2: out = Xb @ W'^T + bias — r4 skeleton, PURE gload_lds staging.
// 256x256 tile, 8 waves (2Mx4N), BK=64, double-buffered 128KB dynamic LDS,
// ONE barrier per K-tile.
// A: 4 gload_lds/wave (32 chunks of 1KB = full 32KB tile; r11 bug was i<2 =
//    half-staged tile) from the pre-swizzled Xb image, per-lane source.
// B: 4 gload_lds/wave from Wp (pre-swizzled source; validated since r4).
// K-loop per wave per tile: {8 vmem issues, 16 ds_read_b128, 64 MFMA, bar}.
// ---------------------------------------------------------------------------
__global__ __launch_bounds__(512, 2) void gemm_bf(
    const bf16* __restrict__ Xb, const bf16* __restrict__ Wp,
    const float* __restrict__ bias, float* __restrict__ out) {
  extern __shared__ __align__(16) char smem[];  // A0 A1 B0 B1 (32KB each)

  const int tid = threadIdx.x;
  const int lane = tid & 63;
  const int w = tid >> 6;   // 0..7
  const int wrow = w >> 2;  // 0..1
  const int wcol = w & 3;   // 0..3

  // XCD-grouped decode (validated: X panel fetched once per XCD).
  const int bid = blockIdx.x;                // 0..511
  const int sq = bid >> 3;                   // 0..63
  const int bm = (bid & 7) + 8 * (sq >> 2);  // 0..127
  const int bn = sq & 3;                     // 0..3

  // A source: per-lane address; lane l supplies image bytes chunk*1024+l*16.
  const bf16* gA = Xb + (size_t)bm * (KT * 16384) + lane * 8;

  // B staging (r4-identical): linear gload_lds dest; pre-swizzled source.
  const bf16* gB = Wp + ((size_t)bn * BN + w * 8 + (lane >> 3)) * IN_F +
                   (((lane & 7) ^ ((lane >> 3) & 7)) * 8);

  // Accumulators preloaded with bias (C/D col = lane&15).
  f32x4 acc[8][4];
#pragma unroll
  for (int n = 0; n < 4; ++n) {
    const float bv = bias[bn * BN + wcol * 64 + n * 16 + (lane & 15)];
#pragma unroll
    for (int m = 0; m < 8; ++m) acc[m][n] = (f32x4){bv, bv, bv, bv};
  }

  // Fragment read geometry (validated: 16-lane groups, 2-way = free).
  const int rl = lane & 15;
  const int rx = rl & 7;
  const int arow0 = wrow * 128 + rl;  // + m*16
  const int brow0 = wcol * 64 + rl;   // + n*16
  const int sl0 = lane >> 4;          // + kk*4

  auto issueA = [&](int t, int buf) {
    const bf16* g = gA + (size_t)t * 16384;  // 32KB image = 16384 bf16
#pragma unroll
    for (int i = 0; i < 4; ++i) {
      const int chunk = i * 8 + w;  // 0..31: full 32KB tile across 8 waves
      __builtin_amdgcn_global_load_lds(
          (const __attribute__((address_space(1))) void*)(g + chunk * 512),
          (__attribute__((address_space(3))) void*)(smem + buf * 32768 +
                                                    chunk * 1024),
          16, 0, 0);
    }
  };
  auto issueB = [&](int t, int buf) {
    const bf16* g = gB + (size_t)t * BK;
    char* dst0 = smem + 65536 + buf * 32768 + w * 1024;  // wave-uniform base
#pragma unroll
    for (int i = 0; i < 4; ++i) {
      __builtin_amdgcn_global_load_lds(
          (const __attribute__((address_space(1))) void*)(g +
                                                          (size_t)i * 64 * IN_F),
          (__attribute__((address_space(3))) void*)(dst0 + i * 8192), 16, 0, 0);
    }
  };
  auto compute = [&](int buf) {
    const char* A = smem + buf * 32768;
    const char* B = smem + 65536 + buf * 32768;
#pragma unroll
    for (int kk = 0; kk < 2; ++kk) {
      const int so = (((kk * 4 + sl0) ^ rx) << 4);
      bf16x8 af[8], bfr[4];
#pragma unroll
      for (int m = 0; m < 8; ++m)
        af[m] =
            *reinterpret_cast<const bf16x8*>(A + (arow0 + m * 16) * 128 + so);
#pragma unroll
      for (int n = 0; n < 4; ++n)
        bfr[n] =
            *reinterpret_cast<const bf16x8*>(B + (brow0 + n * 16) * 128 + so);
      __builtin_amdgcn_s_setprio(1);
#pragma unroll
      for (int m = 0; m < 8; ++m)
#pragma unroll
        for (int n = 0; n < 4; ++n)
          acc[m][n] = __builtin_amdgcn_mfma_f32_16x16x32_bf16(
              af[m], bfr[n], acc[m][n], 0, 0, 0);
      __builtin_amdgcn_s_setprio(0);
    }
  };

  // Prologue: stage tile 0 into buffer 0.
  issueA(0, 0);
  issueB(0, 0);
  __syncthreads();

  // Main loop: one barrier per K-tile; staging has a full compute window.
  for (int t = 0; t < KT; ++t) {
    const int db = t & 1;
    if (t + 1 < KT) {
      issueA(t + 1, db ^ 1);
      issueB(t + 1, db ^ 1);
      __builtin_amdgcn_sched_barrier(0);
    }
    compute(db);
    __syncthreads();
  }

  // Epilogue (validated): C/D col = lane&15, row = (lane>>4)*4 + i.
  const int orow0 = bm * BM + wrow * 128 + (lane >> 4) * 4;
  const int ocol = bn * BN + wcol * 64 + (lane & 15);
#pragma unroll
  for (int m = 0; m < 8; ++m) {
#pragma unroll
    for (int n = 0; n < 4; ++n) {
      const f32x4 v = acc[m][n];
      const size_t base = (size_t)(orow0 + m * 16) * OUT_F + (ocol + n * 16);
#pragma unroll
      for (int i = 0; i < 4; ++i) out[base + (size_t)i * OUT_F] = v[i];
    }
  }
}

// ---------------------------------------------------------------------------
// Fallback GEMM (round-4 kernel, verbatim): used if ws_size can't hold Xb.
// ---------------------------------------------------------------------------
__global__ __launch_bounds__(512, 2) void gemm_r4(
    const float* __restrict__ X, const bf16* __restrict__ Wp,
    const float* __restrict__ bias, float* __restrict__ out) {
  extern __shared__ __align__(16) char smem[];

  const int tid = threadIdx.x;
  const int lane = tid & 63;
  const int w = tid >> 6;
  const int wrow = w >> 2;
  const int wcol = w & 3;

  const int bid = blockIdx.x;
  const int sq = bid >> 3;
  const int bm = (bid & 7) + 8 * (sq >> 2);
  const int bn = sq & 3;

  const float* gA = X + ((size_t)bm * BM + (tid >> 3)) * IN_F + (tid & 7) * 8;
  const int awbyte =
      ((tid >> 3) << 7) + ((((tid & 7) ^ ((tid >> 3) & 7))) << 4);

  const bf16* gB = Wp + ((size_t)bn * BN + w * 8 + (lane >> 3)) * IN_F +
                   (((lane & 7) ^ ((lane >> 3) & 7)) * 8);

  f32x4 acc[8][4];
#pragma unroll
  for (int n = 0; n < 4; ++n) {
    const float bv = bias[bn * BN + wcol * 64 + n * 16 + (lane & 15)];
#pragma unroll
    for (int m = 0; m < 8; ++m) acc[m][n] = (f32x4){bv, bv, bv, bv};
  }

  const int rl = lane & 15;
  const int rx = rl & 7;
  const int arow0 = wrow * 128 + rl;
  const int brow0 = wcol * 64 + rl;
  const int sl0 = lane >> 4;

  f32x4 av[8];

  auto issueA = [&](int t) {
#pragma unroll
    for (int j = 0; j < 4; ++j) {
      const float* p = gA + (size_t)j * 64 * IN_F + (size_t)t * BK;
      av[2 * j] = *reinterpret_cast<const f32x4*>(p);
      av[2 * j + 1] = *reinterpret_cast<const f32x4*>(p + 4);
    }
  };
  auto writeA = [&](int buf) {
    char* base = smem + buf * 32768;
#pragma unroll
    for (int j = 0; j < 4; ++j) {
      bf16x8 o;
#pragma unroll
      for (int q = 0; q < 4; ++q) {
        o[q] = (bf16)av[2 * j][q];
        o[4 + q] = (bf16)av[2 * j + 1][q];
      }
      *reinterpret_cast<bf16x8*>(base + j * 8192 + awbyte) = o;
    }
  };
  auto issueB = [&](int t, int buf) {
    const bf16* g = gB + (size_t)t * BK;
    char* dst0 = smem + 65536 + buf * 32768 + w * 1024;
#pragma unroll
    for (int i = 0; i < 4; ++i) {
      __builtin_amdgcn_global_load_lds(
          (const __attribute__((address_space(1))) void*)(g +
                                                          (size_t)i * 64 * IN_F),
          (__attribute__((address_space(3))) void*)(dst0 + i * 8192), 16, 0, 0);
    }
  };
  auto compute = [&](int buf) {
    const char* A = smem + buf * 32768;
    const char* B = smem + 65536 + buf * 32768;
#pragma unroll
    for (int kk = 0; kk < 2; ++kk) {
      const int so = (((kk * 4 + sl0) ^ rx) << 4);
      bf16x8 af[8], bfr[4];
#pragma unroll
      for (int m = 0; m < 8; ++m)
        af[m] =
            *reinterpret_cast<const bf16x8*>(A + (arow0 + m * 16) * 128 + so);
#pragma unroll
      for (int n = 0; n < 4; ++n)
        bfr[n] =
            *reinterpret_cast<const bf16x8*>(B + (brow0 + n * 16) * 128 + so);
      __builtin_amdgcn_s_setprio(1);
#pragma unroll
      for (int m = 0; m < 8; ++m)
#pragma unroll
        for (int n = 0; n < 4; ++n)
          acc[m][n] = __builtin_amdgcn_mfma_f32_16x16x32_bf16(
              af[m], bfr[n], acc[m][n], 0, 0, 0);
      __builtin_amdgcn_s_setprio(0);
    }
  };

  issueA(0);
  issueB(0, 0);
  writeA(0);
  __syncthreads();

  for (int t = 0; t < KT; ++t) {
    const int db = t & 1;
    const bool more = (t + 1) < KT;
    if (more) {
      issueA(t + 1);
      issueB(t + 1, db ^ 1);
      __builtin_amdgcn_sched_barrier(0);
    }
    compute(db);
    if (more) {
      __builtin_amdgcn_sched_barrier(0);
      writeA(db ^ 1);
      __syncthreads();
    }
  }

  const int orow0 = bm * BM + wrow * 128 + (lane >> 4) * 4;
  const int ocol = bn * BN + wcol * 64 + (lane & 15);
#pragma unroll
  for (int m = 0; m < 8; ++m) {
#pragma unroll
    for (int n = 0; n < 4; ++n) {
      const f32x4 v = acc[m][n];
      const size_t base = (size_t)(orow0 + m * 16) * OUT_F + (ocol + n * 16);
#pragma unroll
      for (int i = 0; i < 4; ++i) out[base + (size_t)i * OUT_F] = v[i];
    }
  }
}

// ---------------------------------------------------------------------------
extern "C" void kernel_launch(void* const* d_in, const int* in_sizes, int n_in,
                              void* d_out, int out_size, void* d_ws,
                              size_t ws_size, hipStream_t stream) {
  const float* x = (const float*)d_in[0];
  const float* weight = (const float*)d_in[1];
  const float* bias = (const float*)d_in[2];
  const int* rrows = (const int*)d_in[3];
  const int* rsrc = (const int*)d_in[4];
  const int* rclones = (const int*)d_in[5];
  float* out = (float*)d_out;

  bf16* Wp = (bf16*)d_ws;                        // 2 MB
  bf16* Xb = (bf16*)((char*)d_ws + (2u << 20));  // 64 MB
  const size_t need = (2u << 20) + (size_t)NTOK * IN_F * 2;

  (void)hipFuncSetAttribute((const void*)gemm_bf,
                            hipFuncAttributeMaxDynamicSharedMemorySize, 131072);
  (void)hipFuncSetAttribute((const void*)gemm_r4,
                            hipFuncAttributeMaxDynamicSharedMemorySize, 131072);

  build_wp<<<dim3(OUT_F), dim3(256), 0, stream>>>(weight, rrows, rsrc, rclones,
                                                  Wp);
  if (ws_size >= need) {
    prep_xb<<<dim3((NTOK / BM) * KT * 2048 / 256), dim3(256), 0, stream>>>(x,
                                                                           Xb);
    gemm_bf<<<dim3((NTOK / BM) * (OUT_F / BN)), dim3(512), 131072, stream>>>(
        Xb, Wp, bias, out);
  } else {
    gemm_r4<<<dim3((NTOK / BM) * (OUT_F / BN)), dim3(512), 131072, stream>>>(
        x, Wp, bias, out);
  }
}